// Round 1
// baseline (495.859 us; speedup 1.0000x reference)
//
#include <hip/hip_runtime.h>

// GRU (reset_after, inference) fused with dense head.
// B=1024 rows, T=512 steps, F=16 features, H=64 hidden.
// One row per block; block = 128 threads = 2 waves.
// lane j (0..63) owns hidden unit j; the k-reduction (over 64 hidden units)
// and the f-reduction (over 16 features) are split across the 2 waves and
// combined through a double-buffered LDS slot (1 barrier per step).
// U/W fragments live in VGPRs (~150/wave); h[k] broadcast via v_readlane.

#define T_ 512
#define F_ 16
#define H_ 64

__device__ __forceinline__ float sigm(float a) {
    return 1.0f / (1.0f + __expf(-a));
}
__device__ __forceinline__ float tanh_fast(float a) {
    // tanh(a) = 1 - 2/(exp(2a)+1); saturates correctly for large |a|
    return 1.0f - 2.0f / (__expf(2.0f * a) + 1.0f);
}

__global__ __launch_bounds__(128, 1) void gru_fused(
    const float* __restrict__ x, const float* __restrict__ W,
    const float* __restrict__ U, const float* __restrict__ b,
    const float* __restrict__ w1, const float* __restrict__ b1,
    const float* __restrict__ gamma_, const float* __restrict__ beta_,
    const float* __restrict__ mmean, const float* __restrict__ mvar,
    const float* __restrict__ w2, const float* __restrict__ b2,
    float* __restrict__ out)
{
    __shared__ float xs[T_ * F_];            // 32 KB: whole x row
    __shared__ float comb[2 * 2 * 64 * 4];   // 4 KB: [parity][wave][lane][az,ar,axh,arh]
    __shared__ float hs[64];

    const int tid = threadIdx.x;
    const int j   = tid & 63;     // hidden unit
    const int w   = tid >> 6;     // wave id 0/1
    const int row = blockIdx.x;

    // ---- stage x[row] into LDS (coalesced float4) ----
    const float4* xr4 = (const float4*)(x + (size_t)row * (T_ * F_));
    float4* xs4 = (float4*)xs;
    #pragma unroll
    for (int i = 0; i < (T_ * F_ / 4) / 128; ++i)   // 16 iters
        xs4[i * 128 + tid] = xr4[i * 128 + tid];

    // ---- U fragment (this wave's k-half), W fragment (this wave's f-half) ----
    float uz[32], ur[32], uh[32];
    const int k0 = w * 32;
    #pragma unroll
    for (int k = 0; k < 32; ++k) {
        uz[k] = U[(k0 + k) * 192 + j];
        ur[k] = U[(k0 + k) * 192 + 64 + j];
        uh[k] = U[(k0 + k) * 192 + 128 + j];
    }
    float wz[8], wr[8], wh[8];
    const int f0 = w * 8;
    #pragma unroll
    for (int f = 0; f < 8; ++f) {
        wz[f] = W[(f0 + f) * 192 + j];
        wr[f] = W[(f0 + f) * 192 + 64 + j];
        wh[f] = W[(f0 + f) * 192 + 128 + j];
    }
    // biases live only in wave 0's partial (pre-summed where possible)
    float bz = 0.f, brr = 0.f, bxh = 0.f, brh = 0.f;
    if (w == 0) {
        bz  = b[j]       + b[192 + j];   // bi_z + br_z
        brr = b[64 + j]  + b[256 + j];   // bi_r + br_r
        bxh = b[128 + j];                // bi_h (stays with x-part)
        brh = b[320 + j];                // br_h (stays with rec-part)
    }

    __syncthreads();   // xs ready

    float h = 0.0f;
    for (int t = 0; t < T_; ++t) {
        float az = bz, ar = brr, axh = bxh, arh = brh;

        // input projection, this wave's f-half (LDS broadcast reads)
        const float* xt = xs + t * F_ + f0;
        #pragma unroll
        for (int f = 0; f < 8; ++f) {
            float xv = xt[f];
            az  = fmaf(xv, wz[f], az);
            ar  = fmaf(xv, wr[f], ar);
            axh = fmaf(xv, wh[f], axh);
        }

        // recurrence, this wave's k-half: h[k] via readlane (SGPR broadcast)
        int hb = __float_as_int(h);
        if (w == 0) {
            #pragma unroll
            for (int k = 0; k < 32; ++k) {
                float hk = __int_as_float(__builtin_amdgcn_readlane(hb, k));
                az  = fmaf(hk, uz[k], az);
                ar  = fmaf(hk, ur[k], ar);
                arh = fmaf(hk, uh[k], arh);
            }
        } else {
            #pragma unroll
            for (int k = 0; k < 32; ++k) {
                float hk = __int_as_float(__builtin_amdgcn_readlane(hb, 32 + k));
                az  = fmaf(hk, uz[k], az);
                ar  = fmaf(hk, ur[k], ar);
                arh = fmaf(hk, uh[k], arh);
            }
        }

        // cross-wave combine (double-buffered on t parity; single barrier)
        const int p = t & 1;
        float4* cw = (float4*)&comb[((p * 2 + w) * 64 + j) * 4];
        *cw = make_float4(az, ar, axh, arh);
        __syncthreads();
        float4 o = *(const float4*)&comb[((p * 2 + (1 - w)) * 64 + j) * 4];
        az += o.x; ar += o.y; axh += o.z; arh += o.w;

        // gates (computed redundantly in both waves so both hold full h)
        float z  = sigm(az);
        float r  = sigm(ar);
        float hh = tanh_fast(fmaf(r, arh, axh));
        h = fmaf(z, h - hh, hh);
    }

    hs[j] = h;            // both waves write identical values (benign)
    __syncthreads();

    // ---- head: y = relu(h @ w1 + b1); BN(inference); out = y @ w2 + b2 ----
    float y = b1[j];
    #pragma unroll 8
    for (int k = 0; k < H_; ++k)
        y = fmaf(hs[k], w1[k * H_ + j], y);
    y = fmaxf(y, 0.0f);
    y = fmaf((y - mmean[j]) * rsqrtf(mvar[j] + 1e-3f), gamma_[j], beta_[j]);

    float acc = y * w2[j];
    #pragma unroll
    for (int off = 32; off > 0; off >>= 1)
        acc += __shfl_down(acc, off, 64);
    if (tid == 0) out[row] = acc + b2[0];
}

extern "C" void kernel_launch(void* const* d_in, const int* in_sizes, int n_in,
                              void* d_out, int out_size, void* d_ws, size_t ws_size,
                              hipStream_t stream) {
    const float* x      = (const float*)d_in[0];
    const float* W      = (const float*)d_in[1];
    const float* U      = (const float*)d_in[2];
    const float* b      = (const float*)d_in[3];
    const float* w1     = (const float*)d_in[4];
    const float* b1     = (const float*)d_in[5];
    const float* gamma_ = (const float*)d_in[6];
    const float* beta_  = (const float*)d_in[7];
    const float* mmean  = (const float*)d_in[8];
    const float* mvar   = (const float*)d_in[9];
    const float* w2     = (const float*)d_in[10];
    const float* b2     = (const float*)d_in[11];
    float* out = (float*)d_out;

    const int B = in_sizes[0] / (T_ * F_);   // 1024
    gru_fused<<<B, 128, 0, stream>>>(x, W, U, b, w1, b1, gamma_, beta_,
                                     mmean, mvar, w2, b2, out);
}